// Round 1
// baseline (14028.989 us; speedup 1.0000x reference)
//
#include <hip/hip_runtime.h>
#include <hip/hip_bf16.h>

#define T_SEQ 2048
#define HID 128
#define CHUNK 16
#define NLAYER 5
#define LSTR 136   // LDS row stride in bf16 elems (pad 8 -> 272B rows, 16B aligned)

typedef __attribute__((ext_vector_type(8))) short short8;
typedef __attribute__((ext_vector_type(4))) float floatx4;

static __device__ __forceinline__ unsigned short f2bf(float f) {
  union { float f; unsigned u; } v; v.f = f;
  unsigned r = v.u + 0x7fffu + ((v.u >> 16) & 1u);   // RNE
  return (unsigned short)(r >> 16);
}
static __device__ __forceinline__ float fsigmoid(float x) {
  float e = __expf(-x);
  return __builtin_amdgcn_rcpf(1.0f + e);
}
static __device__ __forceinline__ float ftanh(float x) {
  float e = __expf(2.0f * x);
  return (e - 1.0f) * __builtin_amdgcn_rcpf(e + 1.0f);
}
static __device__ __forceinline__ floatx4 mfma_bf16(short8 a, short8 b, floatx4 c) {
  return __builtin_amdgcn_mfma_f32_16x16x32_bf16(a, b, c, 0, 0, 0);
}

__global__ __launch_bounds__(256, 1) void gru_pipe(
    const float* __restrict__ inp,
    const float* __restrict__ Whr, const float* __restrict__ Wxr, const float* __restrict__ br,
    const float* __restrict__ Whz, const float* __restrict__ Wxz, const float* __restrict__ bz,
    const float* __restrict__ Whh, const float* __restrict__ Wxh, const float* __restrict__ bh,
    float* __restrict__ out, int* __restrict__ flags, unsigned short* __restrict__ rings,
    int S, int smask)
{
  const int bid   = blockIdx.x;
  const int layer = bid >> 4;      // 0..4
  const int chunk = bid & 15;      // 0..15
  const int r0    = chunk * CHUNK;
  const int tid   = threadIdx.x;
  const int w     = tid >> 6;      // wave 0..3
  const int lane  = tid & 63;
  const int q     = lane >> 4;     // quad 0..3
  const int ln    = lane & 15;
  const int cb    = w * 32;        // this wave's column base (owns 32 cols of each gate)

  __shared__ unsigned short hbuf[16 * LSTR];
  __shared__ unsigned short rbuf[16 * LSTR];
  __shared__ unsigned short xbuf[2][16 * LSTR];

  // ---------------- weight fragments (registers, once) ----------------
  const int wo = layer * HID * HID;
  const int bo = layer * HID;
  short8 Fhr[2][4], Fxr[2][4], Fhz[2][4], Fxz[2][4], Fhh[2][4], Fxh[2][4];
  float brv[2], bzv[2], bhv[2];
  #pragma unroll
  for (int nt = 0; nt < 2; ++nt) {
    const int n = cb + nt * 16 + ln;
    brv[nt] = br[bo + n]; bzv[nt] = bz[bo + n]; bhv[nt] = bh[bo + n];
    #pragma unroll
    for (int kt = 0; kt < 4; ++kt) {
      const int k0 = kt * 32 + q * 8;
      union { short8 v; unsigned short u[8]; } a0, a1, a2, a3, a4, a5;
      #pragma unroll
      for (int j = 0; j < 8; ++j) {
        const int idx = wo + (k0 + j) * HID + n;   // W[k][n], row-major [H,H]
        a0.u[j] = f2bf(Whr[idx]); a1.u[j] = f2bf(Wxr[idx]);
        a2.u[j] = f2bf(Whz[idx]); a3.u[j] = f2bf(Wxz[idx]);
        a4.u[j] = f2bf(Whh[idx]); a5.u[j] = f2bf(Wxh[idx]);
      }
      Fhr[nt][kt] = a0.v; Fxr[nt][kt] = a1.v; Fhz[nt][kt] = a2.v;
      Fxz[nt][kt] = a3.v; Fhh[nt][kt] = a4.v; Fxh[nt][kt] = a5.v;
    }
  }

  // ---------------- FIFO plumbing ----------------
  const int myidx = (layer < 4) ? (layer * 16 + chunk) : 0;
  const int upidx = (layer > 0) ? ((layer - 1) * 16 + chunk) : 0;
  int* pf_prod      = flags + myidx * 32;          // tiles we've published
  int* pf_prod_cons = flags + 2048 + myidx * 32;   // tiles of our ring consumed downstream
  int* pf_up_prod   = flags + upidx * 32;          // upstream published
  int* pf_up_cons   = flags + 2048 + upidx * 32;   // our consumption report
  unsigned short*       my_ring = rings + (size_t)myidx * S * 2048;
  const unsigned short* up_ring = rings + (size_t)upidx * S * 2048;

  const int lrow = (w << 2) + q;   // cooperative tile load: wave w handles rows w*4..w*4+3
  const int lc8  = ln * 8;

  // zero h state buffer
  for (int i = tid; i < 16 * LSTR / 2; i += 256) ((unsigned*)hbuf)[i] = 0u;

  float hc[2][4];                  // exact fp32 h carry, C-layout, this wave's 32 cols
  #pragma unroll
  for (int nt = 0; nt < 2; ++nt)
    #pragma unroll
    for (int i = 0; i < 4; ++i) hc[nt][i] = 0.0f;

  auto load_tile = [&](int tt) {   // wave-cooperative: tile tt -> xbuf[tt&1]
    unsigned short* dst = &xbuf[tt & 1][lrow * LSTR + lc8];
    if (layer == 0) {
      const float* src = inp + ((size_t)(r0 + lrow) * T_SEQ + tt) * HID + lc8;
      float4 p0 = *(const float4*)src;
      float4 p1 = *(const float4*)(src + 4);
      union { short8 v; unsigned short u[8]; } tb;
      tb.u[0] = f2bf(p0.x); tb.u[1] = f2bf(p0.y); tb.u[2] = f2bf(p0.z); tb.u[3] = f2bf(p0.w);
      tb.u[4] = f2bf(p1.x); tb.u[5] = f2bf(p1.y); tb.u[6] = f2bf(p1.z); tb.u[7] = f2bf(p1.w);
      *(short8*)dst = tb.v;
    } else {
      int rdy = 0;
      if (lane == 0) {
        int spins = 0;
        do {
          rdy = __hip_atomic_load(pf_up_prod, __ATOMIC_ACQUIRE, __HIP_MEMORY_SCOPE_AGENT);
          if (rdy >= tt + 1) break;
          __builtin_amdgcn_s_sleep(1);
        } while (++spins < (1 << 22));   // bailout: wrong answer beats a hang
      }
      rdy = __builtin_amdgcn_readfirstlane(rdy);
      const unsigned short* slot = up_ring + (size_t)(tt & smask) * 2048
                                   + (((unsigned)rdy) >> 31);  // always 0; blocks hoisting
      *(short8*)dst = *(const short8*)(slot + lrow * HID + lc8);
    }
  };

  load_tile(0);
  __syncthreads();

  for (int t = 0; t < T_SEQ; ++t) {
    // A-fragments: lane = row m (lane&15), 8 consecutive k at quad*8
    short8 hpA[4], xA[4];
    #pragma unroll
    for (int kt = 0; kt < 4; ++kt) {
      hpA[kt] = *(const short8*)&hbuf[ln * LSTR + kt * 32 + q * 8];
      xA[kt]  = *(const short8*)&xbuf[t & 1][ln * LSTR + kt * 32 + q * 8];
    }
    floatx4 aR[2], aZ[2], aH[2];
    #pragma unroll
    for (int nt = 0; nt < 2; ++nt) {
      floatx4 r = {0,0,0,0}, z = {0,0,0,0}, h = {0,0,0,0};
      #pragma unroll
      for (int kt = 0; kt < 4; ++kt) {
        r = mfma_bf16(hpA[kt], Fhr[nt][kt], r);
        r = mfma_bf16(xA[kt],  Fxr[nt][kt], r);
        z = mfma_bf16(hpA[kt], Fhz[nt][kt], z);
        z = mfma_bf16(xA[kt],  Fxz[nt][kt], z);
        h = mfma_bf16(xA[kt],  Fxh[nt][kt], h);
      }
      aR[nt] = r; aZ[nt] = z; aH[nt] = h;
    }
    // R = sigmoid(.), rp = R*hp -> LDS for A-layout re-read
    #pragma unroll
    for (int nt = 0; nt < 2; ++nt) {
      const int col = cb + nt * 16 + ln;
      #pragma unroll
      for (int i = 0; i < 4; ++i) {
        float rr = fsigmoid(aR[nt][i] + brv[nt]);
        rbuf[(q * 4 + i) * LSTR + col] = f2bf(rr * hc[nt][i]);
      }
    }
    __syncthreads();
    short8 rpA[4];
    #pragma unroll
    for (int kt = 0; kt < 4; ++kt)
      rpA[kt] = *(const short8*)&rbuf[ln * LSTR + kt * 32 + q * 8];
    #pragma unroll
    for (int nt = 0; nt < 2; ++nt) {
      floatx4 h = aH[nt];
      #pragma unroll
      for (int kt = 0; kt < 4; ++kt)
        h = mfma_bf16(rpA[kt], Fhh[nt][kt], h);
      aH[nt] = h;
    }

    if (t + 1 < T_SEQ) load_tile(t + 1);   // prefetch next input tile (overlaps epilogue)

    // backpressure before reusing ring slot
    unsigned wdep = 0;
    if (layer < 4 && t >= S) {
      int c = 0;
      if (lane == 0) {
        int spins = 0;
        do {
          c = __hip_atomic_load(pf_prod_cons, __ATOMIC_ACQUIRE, __HIP_MEMORY_SCOPE_AGENT);
          if (c >= t - S + 1) break;
          __builtin_amdgcn_s_sleep(1);
        } while (++spins < (1 << 22));
      }
      wdep = ((unsigned)__builtin_amdgcn_readfirstlane(c)) >> 31;
    }
    unsigned short* oslot = my_ring + (size_t)(t & smask) * 2048 + wdep;

    // epilogue: Z, h~, ht; fp32 carry stays exact in hc
    #pragma unroll
    for (int nt = 0; nt < 2; ++nt) {
      const int col = cb + nt * 16 + ln;
      #pragma unroll
      for (int i = 0; i < 4; ++i) {
        float zz = fsigmoid(aZ[nt][i] + bzv[nt]);
        float hh = ftanh(aH[nt][i] + bhv[nt]);
        float ht = zz * hh + (1.0f - zz) * hc[nt][i];
        hc[nt][i] = ht;
        const int m = q * 4 + i;
        hbuf[m * LSTR + col] = f2bf(ht);
        if (layer == 4) {
          out[((size_t)(r0 + m) * T_SEQ + t) * HID + col] = ht;
        } else {
          oslot[m * HID + col] = f2bf(ht);
        }
      }
    }
    __syncthreads();   // drains ring stores to L2 + hbuf ready for t+1
    if (tid == 0) {
      __threadfence(); // agent-scope: make ring data visible cross-XCD before flag
      if (layer < 4)
        __hip_atomic_store(pf_prod, t + 1, __ATOMIC_RELAXED, __HIP_MEMORY_SCOPE_AGENT);
      if (layer > 0) {
        int cv = t + 2; if (cv > T_SEQ) cv = T_SEQ;
        __hip_atomic_store(pf_up_cons, cv, __ATOMIC_RELAXED, __HIP_MEMORY_SCOPE_AGENT);
      }
    }
  }
}

extern "C" void kernel_launch(void* const* d_in, const int* in_sizes, int n_in,
                              void* d_out, int out_size, void* d_ws, size_t ws_size,
                              hipStream_t stream) {
  const float* inp = (const float*)d_in[0];
  const float* Whr = (const float*)d_in[1];
  const float* Wxr = (const float*)d_in[2];
  const float* br  = (const float*)d_in[3];
  const float* Whz = (const float*)d_in[4];
  const float* Wxz = (const float*)d_in[5];
  const float* bz  = (const float*)d_in[6];
  const float* Whh = (const float*)d_in[7];
  const float* Wxh = (const float*)d_in[8];
  const float* bh  = (const float*)d_in[9];
  float* out = (float*)d_out;

  // ws layout: 16KB flags (64 prod + 64 cons counters, 128B padded) then 64 rings
  const size_t flag_bytes = 4096 * sizeof(int);
  int* flags = (int*)d_ws;
  unsigned short* rings = (unsigned short*)((char*)d_ws + flag_bytes);
  int S = 64;   // slots per ring (pow2); shrink if ws is small
  while (S > 1 && flag_bytes + (size_t)64 * S * 4096 > ws_size) S >>= 1;
  const int smask = S - 1;

  hipMemsetAsync(d_ws, 0, flag_bytes, stream);   // flags must be zero every call (ws re-poisoned)

  dim3 grid(NLAYER * 16), block(256);
  hipLaunchKernelGGL(gru_pipe, grid, block, 0, stream,
                     inp, Whr, Wxr, br, Whz, Wxz, bz, Whh, Wxh, bh,
                     out, flags, rings, S, smask);
}